// Round 1
// baseline (26.344 us; speedup 1.0000x reference)
//
#include <hip/hip_runtime.h>

#define DEV __device__ __forceinline__

DEV float fast_rcp(float x) { return __builtin_amdgcn_rcpf(x); }

DEV float fast_tanh(float x) {
    // tanh(x) = 1 - 2/(exp(2x)+1); clamp so exp never overflows
    x = fminf(fmaxf(x, -9.0f), 9.0f);
    float e = __expf(2.0f * x);
    return 1.0f - 2.0f * fast_rcp(e + 1.0f);
}

DEV float fast_sigmoid(float x) {
    return fast_rcp(1.0f + __expf(-x));
}

template <int IN, int OUT, bool HAS_BIAS, bool TANH>
DEV void layer(const float* __restrict__ w, const float* __restrict__ b,
               const float (&in)[IN], float (&out)[OUT]) {
    #pragma unroll
    for (int o = 0; o < OUT; ++o) {
        float acc = HAS_BIAS ? b[o] : 0.0f;
        #pragma unroll
        for (int i = 0; i < IN; ++i) acc = fmaf(in[i], w[o * IN + i], acc);
        out[o] = TANH ? fast_tanh(acc) : acc;
    }
}

__global__ __launch_bounds__(128)
void qcnn_fused_kernel(const float* __restrict__ x,
                       const float* __restrict__ w_fm, const float* __restrict__ b_fm,
                       const float* __restrict__ w_c1, const float* __restrict__ b_c1,
                       const float* __restrict__ w_p1, const float* __restrict__ b_p1,
                       const float* __restrict__ w_c2, const float* __restrict__ b_c2,
                       const float* __restrict__ w_p2, const float* __restrict__ b_p2,
                       const float* __restrict__ w_c3, const float* __restrict__ b_c3,
                       const float* __restrict__ w_q,  const float* __restrict__ w_k,
                       const float* __restrict__ w_v,
                       const float* __restrict__ w_fc, const float* __restrict__ b_fc,
                       float* __restrict__ out) {
    const int b = blockIdx.x;    // batch 0..2047
    const int s = threadIdx.x;   // token 0..127

    // K rows and V rows for this batch, one float4 per token.
    __shared__ float4 k_lds[128];
    __shared__ float4 v_lds[128];

    // ---- load x[b][s][0:8] (32 B/thread, coalesced) ----
    const float* xp = x + ((size_t)b * 128 + (size_t)s) * 8;
    float4 x0 = *reinterpret_cast<const float4*>(xp);
    float4 x1 = *reinterpret_cast<const float4*>(xp + 4);
    float xin[8] = {x0.x, x0.y, x0.z, x0.w, x1.x, x1.y, x1.z, x1.w};

    // ---- MLP tower, fully in registers; weights via uniform (scalar) loads ----
    float h1[16], h2[16], h3[12], h4[8], h5[4], h6[4];
    layer<8, 16, true, true>(w_fm, b_fm, xin, h1);
    layer<16, 16, true, true>(w_c1, b_c1, h1, h2);
    layer<16, 12, true, true>(w_p1, b_p1, h2, h3);
    layer<12, 8, true, true>(w_c2, b_c2, h3, h4);
    layer<8, 4, true, true>(w_p2, b_p2, h4, h5);
    layer<4, 4, true, true>(w_c3, b_c3, h5, h6);

    float qv[4], kv[4], vv[4];
    layer<4, 4, false, false>(w_q, nullptr, h6, qv);
    layer<4, 4, false, false>(w_k, nullptr, h6, kv);
    layer<4, 4, false, false>(w_v, nullptr, h6, vv);

    k_lds[s] = make_float4(kv[0], kv[1], kv[2], kv[3]);
    v_lds[s] = make_float4(vv[0], vv[1], vv[2], vv[3]);
    __syncthreads();

    // ---- attention row s: single-pass softmax (scores bounded by ~8, no max needed) ----
    const float q0 = qv[0] * 0.5f, q1 = qv[1] * 0.5f, q2 = qv[2] * 0.5f, q3 = qv[3] * 0.5f;
    float denom = 0.0f;
    float a0 = 0.0f, a1 = 0.0f, a2 = 0.0f, a3 = 0.0f;
    #pragma unroll 8
    for (int j = 0; j < 128; ++j) {
        float4 kj = k_lds[j];   // wave-uniform address -> LDS broadcast
        float4 vj = v_lds[j];
        float sc = q0 * kj.x + q1 * kj.y + q2 * kj.z + q3 * kj.w;
        float e = __expf(sc);
        denom += e;
        a0 = fmaf(e, vj.x, a0);
        a1 = fmaf(e, vj.y, a1);
        a2 = fmaf(e, vj.z, a2);
        a3 = fmaf(e, vj.w, a3);
    }
    float inv = fast_rcp(denom);

    // ---- fc (4->1) + sigmoid ----
    float z = b_fc[0];
    z = fmaf(a0 * inv, w_fc[0], z);
    z = fmaf(a1 * inv, w_fc[1], z);
    z = fmaf(a2 * inv, w_fc[2], z);
    z = fmaf(a3 * inv, w_fc[3], z);
    out[(size_t)b * 128 + (size_t)s] = fast_sigmoid(z);
}

extern "C" void kernel_launch(void* const* d_in, const int* in_sizes, int n_in,
                              void* d_out, int out_size, void* d_ws, size_t ws_size,
                              hipStream_t stream) {
    const float* x    = (const float*)d_in[0];
    const float* w_fm = (const float*)d_in[1];
    const float* b_fm = (const float*)d_in[2];
    const float* w_c1 = (const float*)d_in[3];
    const float* b_c1 = (const float*)d_in[4];
    const float* w_p1 = (const float*)d_in[5];
    const float* b_p1 = (const float*)d_in[6];
    const float* w_c2 = (const float*)d_in[7];
    const float* b_c2 = (const float*)d_in[8];
    const float* w_p2 = (const float*)d_in[9];
    const float* b_p2 = (const float*)d_in[10];
    const float* w_c3 = (const float*)d_in[11];
    const float* b_c3 = (const float*)d_in[12];
    const float* w_q  = (const float*)d_in[13];
    const float* w_k  = (const float*)d_in[14];
    const float* w_v  = (const float*)d_in[15];
    const float* w_fc = (const float*)d_in[16];
    const float* b_fc = (const float*)d_in[17];
    float* out = (float*)d_out;

    dim3 grid(2048);   // one workgroup per batch
    dim3 block(128);   // one thread per token
    qcnn_fused_kernel<<<grid, block, 0, stream>>>(
        x, w_fm, b_fm, w_c1, b_c1, w_p1, b_p1, w_c2, b_c2,
        w_p2, b_p2, w_c3, b_c3, w_q, w_k, w_v, w_fc, b_fc, out);
}

// Round 2
// 25.269 us; speedup vs baseline: 1.0426x; 1.0426x over previous
//
#include <hip/hip_runtime.h>

#define DEV __device__ __forceinline__

typedef _Float16 h2 __attribute__((ext_vector_type(2)));

DEV float fast_rcp(float x) { return __builtin_amdgcn_rcpf(x); }

DEV float fexp2(float x) {
#if __has_builtin(__builtin_amdgcn_exp2f)
    return __builtin_amdgcn_exp2f(x);
#else
    float r; asm("v_exp_f32 %0, %1" : "=v"(r) : "v"(x)); return r;
#endif
}

DEV float dot2acc(h2 a, h2 b, float c) {
#if __has_builtin(__builtin_amdgcn_fdot2)
    return __builtin_amdgcn_fdot2(a, b, c, false);
#else
    return c + (float)a.x * (float)b.x + (float)a.y * (float)b.y;
#endif
}

// tanh(x) = 1 - 2/(exp2(x*2*log2e)+1); no clamp needed:
//   x->+inf: exp2->inf, rcp(inf)=0 -> 1.  x->-inf: exp2->0, rcp(1)=1 -> -1.
DEV float fast_tanh(float x) {
    float e = fexp2(x * 2.885390082f);
    return 1.0f - 2.0f * fast_rcp(e + 1.0f);
}

DEV float fast_sigmoid(float x) {
    return fast_rcp(1.0f + fexp2(x * -1.442695041f));
}

template <int IN, int OUT, bool HAS_BIAS, bool TANH>
DEV void layer(const float* __restrict__ w, const float* __restrict__ b,
               const float (&in)[IN], float (&out)[OUT]) {
    #pragma unroll
    for (int o = 0; o < OUT; ++o) {
        float acc = HAS_BIAS ? b[o] : 0.0f;
        #pragma unroll
        for (int i = 0; i < IN; ++i) acc = fmaf(in[i], w[o * IN + i], acc);
        out[o] = TANH ? fast_tanh(acc) : acc;
    }
}

__global__ __launch_bounds__(128)
void qcnn_fused_kernel(const float* __restrict__ x,
                       const float* __restrict__ w_fm, const float* __restrict__ b_fm,
                       const float* __restrict__ w_c1, const float* __restrict__ b_c1,
                       const float* __restrict__ w_p1, const float* __restrict__ b_p1,
                       const float* __restrict__ w_c2, const float* __restrict__ b_c2,
                       const float* __restrict__ w_p2, const float* __restrict__ b_p2,
                       const float* __restrict__ w_c3, const float* __restrict__ b_c3,
                       const float* __restrict__ w_q,  const float* __restrict__ w_k,
                       const float* __restrict__ w_v,
                       const float* __restrict__ w_fc, const float* __restrict__ b_fc,
                       float* __restrict__ out) {
    const int b = blockIdx.x;    // batch 0..2047
    const int t = threadIdx.x;   // token 0..127

    // Packed fp16 K+V per token: x=k01 y=k23 z=v01 w=v23 (16 B -> 1 ds_read_b128)
    __shared__ uint4 kvbuf[128];

    // ---- load x[b][t][0:8] (32 B/thread, coalesced) ----
    const float* xp = x + ((size_t)b * 128 + (size_t)t) * 8;
    float4 x0 = *reinterpret_cast<const float4*>(xp);
    float4 x1 = *reinterpret_cast<const float4*>(xp + 4);
    float xin[8] = {x0.x, x0.y, x0.z, x0.w, x1.x, x1.y, x1.z, x1.w};

    // ---- MLP tower in registers; weights via uniform scalar loads ----
    float h1[16], h2a[16], h3[12], h4[8], h5[4], h6[4];
    layer<8, 16, true, true>(w_fm, b_fm, xin, h1);
    layer<16, 16, true, true>(w_c1, b_c1, h1, h2a);
    layer<16, 12, true, true>(w_p1, b_p1, h2a, h3);
    layer<12, 8, true, true>(w_c2, b_c2, h3, h4);
    layer<8, 4, true, true>(w_p2, b_p2, h4, h5);
    layer<4, 4, true, true>(w_c3, b_c3, h5, h6);

    float qv[4], kk[4], vv[4];
    layer<4, 4, false, false>(w_q, nullptr, h6, qv);
    layer<4, 4, false, false>(w_k, nullptr, h6, kk);
    layer<4, 4, false, false>(w_v, nullptr, h6, vv);

    // pack K,V to fp16
    h2 pk01 = {(_Float16)kk[0], (_Float16)kk[1]};
    h2 pk23 = {(_Float16)kk[2], (_Float16)kk[3]};
    h2 pv01 = {(_Float16)vv[0], (_Float16)vv[1]};
    h2 pv23 = {(_Float16)vv[2], (_Float16)vv[3]};
    uint4 pk;
    pk.x = __builtin_bit_cast(unsigned, pk01);
    pk.y = __builtin_bit_cast(unsigned, pk23);
    pk.z = __builtin_bit_cast(unsigned, pv01);
    pk.w = __builtin_bit_cast(unsigned, pv23);
    kvbuf[t] = pk;

    // q scaled by log2(e)/2 (folds softmax 1/sqrt(4) and exp->exp2), fp16
    const float QS = 0.7213475204f;
    h2 q01 = {(_Float16)(qv[0] * QS), (_Float16)(qv[1] * QS)};
    h2 q23 = {(_Float16)(qv[2] * QS), (_Float16)(qv[3] * QS)};

    __syncthreads();

    // ---- attention: lane pair (2p, 2p+1) covers rows {2p, 2p+1};
    //      even lane does j in [0,64), odd lane j in [64,128). ----
    unsigned q01u = __builtin_bit_cast(unsigned, q01);
    unsigned q23u = __builtin_bit_cast(unsigned, q23);
    unsigned q01o = __shfl_xor(q01u, 1);
    unsigned q23o = __shfl_xor(q23u, 1);
    const bool odd = (t & 1);
    // row r0 = 2p (owned by even lane), row r1 = 2p+1 (owned by odd lane)
    h2 q01_r0 = __builtin_bit_cast(h2, odd ? q01o : q01u);
    h2 q23_r0 = __builtin_bit_cast(h2, odd ? q23o : q23u);
    h2 q01_r1 = __builtin_bit_cast(h2, odd ? q01u : q01o);
    h2 q23_r1 = __builtin_bit_cast(h2, odd ? q23u : q23o);

    const uint4* __restrict__ base = kvbuf + (odd ? 64 : 0);
    float d0 = 0.f, d1 = 0.f;
    float a00 = 0.f, a01 = 0.f, a02 = 0.f, a03 = 0.f;
    float a10 = 0.f, a11 = 0.f, a12 = 0.f, a13 = 0.f;
    #pragma unroll 8
    for (int j = 0; j < 64; ++j) {
        uint4 c = base[j];   // 2-address wave read (free 2-way broadcast)
        h2 k01 = __builtin_bit_cast(h2, c.x);
        h2 k23 = __builtin_bit_cast(h2, c.y);
        h2 v01 = __builtin_bit_cast(h2, c.z);
        h2 v23 = __builtin_bit_cast(h2, c.w);
        float s0 = dot2acc(q01_r0, k01, dot2acc(q23_r0, k23, 0.f));
        float s1 = dot2acc(q01_r1, k01, dot2acc(q23_r1, k23, 0.f));
        float e0 = fexp2(s0);
        float e1 = fexp2(s1);
        float v0 = (float)v01.x, v1 = (float)v01.y;
        float v2 = (float)v23.x, v3 = (float)v23.y;
        d0 += e0; d1 += e1;
        a00 = fmaf(e0, v0, a00); a01 = fmaf(e0, v1, a01);
        a02 = fmaf(e0, v2, a02); a03 = fmaf(e0, v3, a03);
        a10 = fmaf(e1, v0, a10); a11 = fmaf(e1, v1, a11);
        a12 = fmaf(e1, v2, a12); a13 = fmaf(e1, v3, a13);
    }

    // combine lane-pair partials (each row's j-halves live in adjacent lanes)
    d0  += __shfl_xor(d0, 1);   d1  += __shfl_xor(d1, 1);
    a00 += __shfl_xor(a00, 1);  a01 += __shfl_xor(a01, 1);
    a02 += __shfl_xor(a02, 1);  a03 += __shfl_xor(a03, 1);
    a10 += __shfl_xor(a10, 1);  a11 += __shfl_xor(a11, 1);
    a12 += __shfl_xor(a12, 1);  a13 += __shfl_xor(a13, 1);

    // lane t finalizes row t: even -> r0 data, odd -> r1 data
    float dd = odd ? d1 : d0;
    float A0 = odd ? a10 : a00;
    float A1 = odd ? a11 : a01;
    float A2 = odd ? a12 : a02;
    float A3 = odd ? a13 : a03;
    float inv = fast_rcp(dd);

    float z = b_fc[0];
    z = fmaf(A0 * inv, w_fc[0], z);
    z = fmaf(A1 * inv, w_fc[1], z);
    z = fmaf(A2 * inv, w_fc[2], z);
    z = fmaf(A3 * inv, w_fc[3], z);
    out[(size_t)b * 128 + (size_t)t] = fast_sigmoid(z);
}

extern "C" void kernel_launch(void* const* d_in, const int* in_sizes, int n_in,
                              void* d_out, int out_size, void* d_ws, size_t ws_size,
                              hipStream_t stream) {
    const float* x    = (const float*)d_in[0];
    const float* w_fm = (const float*)d_in[1];
    const float* b_fm = (const float*)d_in[2];
    const float* w_c1 = (const float*)d_in[3];
    const float* b_c1 = (const float*)d_in[4];
    const float* w_p1 = (const float*)d_in[5];
    const float* b_p1 = (const float*)d_in[6];
    const float* w_c2 = (const float*)d_in[7];
    const float* b_c2 = (const float*)d_in[8];
    const float* w_p2 = (const float*)d_in[9];
    const float* b_p2 = (const float*)d_in[10];
    const float* w_c3 = (const float*)d_in[11];
    const float* b_c3 = (const float*)d_in[12];
    const float* w_q  = (const float*)d_in[13];
    const float* w_k  = (const float*)d_in[14];
    const float* w_v  = (const float*)d_in[15];
    const float* w_fc = (const float*)d_in[16];
    const float* b_fc = (const float*)d_in[17];
    float* out = (float*)d_out;

    dim3 grid(2048);   // one workgroup per batch
    dim3 block(128);   // one thread per token
    qcnn_fused_kernel<<<grid, block, 0, stream>>>(
        x, w_fm, b_fm, w_c1, b_c1, w_p1, b_p1, w_c2, b_c2,
        w_p2, b_p2, w_c3, b_c3, w_q, w_k, w_v, w_fc, b_fc, out);
}